// Round 2
// baseline (3130.828 us; speedup 1.0000x reference)
//
#include <hip/hip_runtime.h>
#include <hip/hip_bf16.h>

#define N_NODES 100000
#define N_EDGES 1600000
#define IN_CH 256
#define OUT_CH 128

typedef __attribute__((ext_vector_type(8))) short short8;
typedef __attribute__((ext_vector_type(4))) float floatx4;

union bfu { __hip_bfloat16 b; unsigned short u; };

__device__ inline unsigned short f2bf(float v) {
    bfu cv; cv.b = __float2bfloat16(v); return cv.u;
}
__device__ inline float bf2f(unsigned short u) {
    bfu cv; cv.u = u; return __bfloat162float(cv.b);
}

// ---------- degree / dinv ----------
__global__ void k_init_deg(float* deg) {
    int i = blockIdx.x * 256 + threadIdx.x;
    if (i < N_NODES) deg[i] = 1.0f;   // self-loop
}

__global__ void k_count_deg(const int* __restrict__ col, float* __restrict__ deg) {
    int e = blockIdx.x * 256 + threadIdx.x;
    if (e < N_EDGES) atomicAdd(&deg[col[e]], 1.0f);
}

__global__ void k_dinv(float* deg) {
    int i = blockIdx.x * 256 + threadIdx.x;
    if (i < N_NODES) deg[i] = rsqrtf(deg[i]);   // deg >= 1 always
}

// ---------- W (fp32, [256,128]) -> transposed bf16 hi/lo Wt[n][k] ----------
__global__ void k_prep_w(const float* __restrict__ W,
                         unsigned short* __restrict__ wt_hi,
                         unsigned short* __restrict__ wt_lo) {
    int t = blockIdx.x * 256 + threadIdx.x;
    if (t >= IN_CH * OUT_CH) return;
    int k = t >> 7, n = t & 127;          // W row-major [k][n]
    float w = W[t];
    unsigned short hi = f2bf(w);
    float lo = w - bf2f(hi);
    wt_hi[(size_t)n * IN_CH + k] = hi;
    wt_lo[(size_t)n * IN_CH + k] = f2bf(lo);
}

// ---------- h = x @ W  (fp32 in via split-bf16 MFMA, fp32 out) ----------
// One wave per 16x16 tile. A[m=lane&15][k=quad*8+j], B[k=quad*8+j][n=lane&15],
// D: row=quad*4+reg, col=lane&15 (verified layouts, guide §3).
__global__ __launch_bounds__(256) void k_gemm(const float* __restrict__ x,
                                              const unsigned short* __restrict__ wt_hi,
                                              const unsigned short* __restrict__ wt_lo,
                                              float* __restrict__ h) {
    int wave = (blockIdx.x * 256 + threadIdx.x) >> 6;   // 0..49999
    int lane = threadIdx.x & 63;
    int mtile = wave >> 3;          // 0..6249
    int ntile = wave & 7;           // 0..7
    int m0 = mtile * 16, n0 = ntile * 16;
    int r15 = lane & 15;
    int quad = lane >> 4;

    const float* xa = x + (size_t)(m0 + r15) * IN_CH + quad * 8;
    const unsigned short* bhp = wt_hi + (size_t)(n0 + r15) * IN_CH + quad * 8;
    const unsigned short* blp = wt_lo + (size_t)(n0 + r15) * IN_CH + quad * 8;

    floatx4 acc = {0.f, 0.f, 0.f, 0.f};
    for (int k0 = 0; k0 < IN_CH; k0 += 32) {
        float4 xv0 = *(const float4*)(xa + k0);
        float4 xv1 = *(const float4*)(xa + k0 + 4);
        float xs[8] = {xv0.x, xv0.y, xv0.z, xv0.w, xv1.x, xv1.y, xv1.z, xv1.w};
        short8 ah, al;
#pragma unroll
        for (int j = 0; j < 8; ++j) {
            unsigned short hi = f2bf(xs[j]);
            ah[j] = (short)hi;
            al[j] = (short)f2bf(xs[j] - bf2f(hi));
        }
        short8 bh = *(const short8*)(bhp + k0);
        short8 bl = *(const short8*)(blp + k0);
        acc = __builtin_amdgcn_mfma_f32_16x16x32_bf16(ah, bh, acc, 0, 0, 0);
        acc = __builtin_amdgcn_mfma_f32_16x16x32_bf16(ah, bl, acc, 0, 0, 0);
        acc = __builtin_amdgcn_mfma_f32_16x16x32_bf16(al, bh, acc, 0, 0, 0);
    }
#pragma unroll
    for (int r = 0; r < 4; ++r)
        h[(size_t)(m0 + quad * 4 + r) * OUT_CH + n0 + r15] = acc[r];
}

// ---------- agg = h * dinv^2 + b  (self-loop + bias, also inits agg) ----------
__global__ __launch_bounds__(256) void k_agg_init(const float* __restrict__ h,
                                                  const float* __restrict__ dinv,
                                                  const float* __restrict__ b,
                                                  float* __restrict__ agg) {
    int t = blockIdx.x * 256 + threadIdx.x;          // one float4 per thread
    if (t >= N_NODES * OUT_CH / 4) return;
    int node = t >> 5;                               // 32 float4 per node
    int c4 = t & 31;
    float d = dinv[node];
    float w = d * d;
    float4 hv = ((const float4*)h)[t];
    float4 bv = ((const float4*)b)[c4];
    float4 o;
    o.x = hv.x * w + bv.x;
    o.y = hv.y * w + bv.y;
    o.z = hv.z * w + bv.z;
    o.w = hv.w * w + bv.w;
    ((float4*)agg)[t] = o;
}

// ---------- edge scatter: agg[c] += h[r] * dinv[r]*dinv[c] ----------
// 32 lanes per edge, 4 channels per lane.
__global__ __launch_bounds__(256) void k_scatter(const int* __restrict__ rows,
                                                 const int* __restrict__ cols,
                                                 const float* __restrict__ h,
                                                 const float* __restrict__ dinv,
                                                 float* __restrict__ agg) {
    long long t = (long long)blockIdx.x * 256 + threadIdx.x;
    int e = (int)(t >> 5);
    int l = (int)(t & 31);
    if (e >= N_EDGES) return;
    int r = rows[e], c = cols[e];
    float w = dinv[r] * dinv[c];
    float4 hv = ((const float4*)(h + (size_t)r * OUT_CH))[l];
    float* ap = agg + (size_t)c * OUT_CH + l * 4;
    atomicAdd(ap + 0, hv.x * w);
    atomicAdd(ap + 1, hv.y * w);
    atomicAdd(ap + 2, hv.z * w);
    atomicAdd(ap + 3, hv.w * w);
}

// ---------- per-node minmax scale + L2 normalize ----------
__global__ __launch_bounds__(256) void k_finalize(const float* __restrict__ agg,
                                                  float* __restrict__ out) {
    int node = (blockIdx.x * 256 + threadIdx.x) >> 6;   // one wave per node
    int lane = threadIdx.x & 63;
    if (node >= N_NODES) return;
    float2 v = ((const float2*)(agg + (size_t)node * OUT_CH))[lane];
    float lmin = fminf(v.x, v.y), lmax = fmaxf(v.x, v.y);
#pragma unroll
    for (int m = 32; m; m >>= 1) {
        lmin = fminf(lmin, __shfl_xor(lmin, m, 64));
        lmax = fmaxf(lmax, __shfl_xor(lmax, m, 64));
    }
    float scale = 1.0f / (lmax - lmin);
    float zx = (v.x - lmin) * scale;
    float zy = (v.y - lmin) * scale;
    float ss = zx * zx + zy * zy;
#pragma unroll
    for (int m = 32; m; m >>= 1) ss += __shfl_xor(ss, m, 64);
    float inv = 1.0f / fmaxf(sqrtf(ss), 1e-12f);
    float2 o;
    o.x = zx * inv;
    o.y = zy * inv;
    ((float2*)(out + (size_t)node * OUT_CH))[lane] = o;
}

extern "C" void kernel_launch(void* const* d_in, const int* in_sizes, int n_in,
                              void* d_out, int out_size, void* d_ws, size_t ws_size,
                              hipStream_t stream) {
    const float* x = (const float*)d_in[0];        // fp32 [N, 256]
    const int* ei = (const int*)d_in[1];           // int32 [2, E]
    const float* W = (const float*)d_in[2];        // fp32 [256, 128]
    const float* b = (const float*)d_in[3];        // fp32 [128]
    float* out = (float*)d_out;                    // fp32 [N, 128]

    char* ws = (char*)d_ws;
    float* dinv = (float*)ws;                                        // N floats
    size_t off = ((size_t)N_NODES * 4 + 255) & ~(size_t)255;         // 400128
    unsigned short* wt_hi = (unsigned short*)(ws + off);             // 32768 u16
    unsigned short* wt_lo = wt_hi + (size_t)IN_CH * OUT_CH;          // 32768 u16
    float* h = (float*)(ws + off + 2 * (size_t)IN_CH * OUT_CH * 2);  // N*128 f
    float* agg = h + (size_t)N_NODES * OUT_CH;                       // N*128 f

    const int* rows = ei;
    const int* cols = ei + N_EDGES;

    k_init_deg<<<(N_NODES + 255) / 256, 256, 0, stream>>>(dinv);
    k_count_deg<<<(N_EDGES + 255) / 256, 256, 0, stream>>>(cols, dinv);
    k_dinv<<<(N_NODES + 255) / 256, 256, 0, stream>>>(dinv);

    k_prep_w<<<(IN_CH * OUT_CH + 255) / 256, 256, 0, stream>>>(W, wt_hi, wt_lo);
    k_gemm<<<12500, 256, 0, stream>>>(x, wt_hi, wt_lo, h);           // 50000 waves

    k_agg_init<<<(N_NODES * OUT_CH / 4 + 255) / 256, 256, 0, stream>>>(h, dinv, b, agg);
    k_scatter<<<(int)(((long long)N_EDGES * 32 + 255) / 256), 256, 0, stream>>>(rows, cols, h, dinv, agg);

    k_finalize<<<(N_NODES + 3) / 4, 256, 0, stream>>>(agg, out);
}

// Round 3
// 604.548 us; speedup vs baseline: 5.1788x; 5.1788x over previous
//
#include <hip/hip_runtime.h>
#include <hip/hip_bf16.h>

#define N_NODES 100000
#define N_EDGES 1600000
#define IN_CH 256
#define OUT_CH 128
#define NB 391   // ceil(N_NODES/256)

typedef __attribute__((ext_vector_type(8))) short short8;
typedef __attribute__((ext_vector_type(4))) float floatx4;

union bfu { __hip_bfloat16 b; unsigned short u; };

__device__ inline unsigned short f2bf(float v) {
    bfu cv; cv.b = __float2bfloat16(v); return cv.u;
}
__device__ inline float bf2f(unsigned short u) {
    bfu cv; cv.u = u; return __bfloat162float(cv.b);
}

// ---------- CSR build: histogram ----------
__global__ void k_zero(int* cnt) {
    int i = blockIdx.x * 256 + threadIdx.x;
    if (i < N_NODES) cnt[i] = 0;
}

__global__ void k_hist(const int* __restrict__ cols, int* __restrict__ cnt) {
    int e = blockIdx.x * 256 + threadIdx.x;
    if (e < N_EDGES) atomicAdd(&cnt[cols[e]], 1);
}

// per-block sums of cnt
__global__ __launch_bounds__(256) void k_scan1(const int* __restrict__ cnt, int* __restrict__ bsum) {
    __shared__ int s[256];
    int t = threadIdx.x;
    int i = blockIdx.x * 256 + t;
    s[t] = (i < N_NODES) ? cnt[i] : 0;
    __syncthreads();
#pragma unroll
    for (int off = 128; off; off >>= 1) {
        if (t < off) s[t] += s[t + off];
        __syncthreads();
    }
    if (t == 0) bsum[blockIdx.x] = s[0];
}

// exclusive scan of the 391 block sums (single block)
__global__ __launch_bounds__(512) void k_scan2(int* bsum) {
    __shared__ int s[512];
    int t = threadIdx.x;
    int v = (t < NB) ? bsum[t] : 0;
    s[t] = v;
    __syncthreads();
    for (int off = 1; off < 512; off <<= 1) {
        int u = (t >= off) ? s[t - off] : 0;
        __syncthreads();
        s[t] += u;
        __syncthreads();
    }
    if (t < NB) bsum[t] = s[t] - v;   // exclusive
}

// per-block exclusive scan + block offset -> base, cursor; also dinv
__global__ __launch_bounds__(256) void k_scan3(const int* __restrict__ cnt,
                                               const int* __restrict__ bsum,
                                               int* __restrict__ base,
                                               int* __restrict__ cursor,
                                               float* __restrict__ dinv) {
    __shared__ int s[256];
    int t = threadIdx.x;
    int i = blockIdx.x * 256 + t;
    int v = (i < N_NODES) ? cnt[i] : 0;
    s[t] = v;
    __syncthreads();
    for (int off = 1; off < 256; off <<= 1) {
        int u = (t >= off) ? s[t - off] : 0;
        __syncthreads();
        s[t] += u;
        __syncthreads();
    }
    if (i < N_NODES) {
        int b = bsum[blockIdx.x] + s[t] - v;   // exclusive position
        base[i] = b;
        cursor[i] = b;
        dinv[i] = rsqrtf((float)(v + 1));      // self-loop included
    }
}

// scatter edges into CSR order, storing (src, dinv[src])
__global__ void k_sort_edges(const int* __restrict__ rows, const int* __restrict__ cols,
                             const float* __restrict__ dinv,
                             int* __restrict__ cursor, int2* __restrict__ es) {
    int e = blockIdx.x * 256 + threadIdx.x;
    if (e >= N_EDGES) return;
    int c = cols[e], r = rows[e];
    int pos = atomicAdd(&cursor[c], 1);
    es[pos] = make_int2(r, __float_as_int(dinv[r]));
}

// ---------- W (fp32, [256,128]) -> transposed bf16 hi/lo Wt[n][k] ----------
__global__ void k_prep_w(const float* __restrict__ W,
                         unsigned short* __restrict__ wt_hi,
                         unsigned short* __restrict__ wt_lo) {
    int t = blockIdx.x * 256 + threadIdx.x;
    if (t >= IN_CH * OUT_CH) return;
    int k = t >> 7, n = t & 127;          // W row-major [k][n]
    float w = W[t];
    unsigned short hi = f2bf(w);
    float lo = w - bf2f(hi);
    wt_hi[(size_t)n * IN_CH + k] = hi;
    wt_lo[(size_t)n * IN_CH + k] = f2bf(lo);
}

// ---------- h = x @ W  (fp32 in via split-bf16 MFMA, fp32 out) ----------
__global__ __launch_bounds__(256) void k_gemm(const float* __restrict__ x,
                                              const unsigned short* __restrict__ wt_hi,
                                              const unsigned short* __restrict__ wt_lo,
                                              float* __restrict__ h) {
    int wave = (blockIdx.x * 256 + threadIdx.x) >> 6;   // 0..49999
    int lane = threadIdx.x & 63;
    int mtile = wave >> 3;          // 0..6249
    int ntile = wave & 7;           // 0..7
    int m0 = mtile * 16, n0 = ntile * 16;
    int r15 = lane & 15;
    int quad = lane >> 4;

    const float* xa = x + (size_t)(m0 + r15) * IN_CH + quad * 8;
    const unsigned short* bhp = wt_hi + (size_t)(n0 + r15) * IN_CH + quad * 8;
    const unsigned short* blp = wt_lo + (size_t)(n0 + r15) * IN_CH + quad * 8;

    floatx4 acc = {0.f, 0.f, 0.f, 0.f};
    for (int k0 = 0; k0 < IN_CH; k0 += 32) {
        float4 xv0 = *(const float4*)(xa + k0);
        float4 xv1 = *(const float4*)(xa + k0 + 4);
        float xs[8] = {xv0.x, xv0.y, xv0.z, xv0.w, xv1.x, xv1.y, xv1.z, xv1.w};
        short8 ah, al;
#pragma unroll
        for (int j = 0; j < 8; ++j) {
            unsigned short hi = f2bf(xs[j]);
            ah[j] = (short)hi;
            al[j] = (short)f2bf(xs[j] - bf2f(hi));
        }
        short8 bh = *(const short8*)(bhp + k0);
        short8 bl = *(const short8*)(blp + k0);
        acc = __builtin_amdgcn_mfma_f32_16x16x32_bf16(ah, bh, acc, 0, 0, 0);
        acc = __builtin_amdgcn_mfma_f32_16x16x32_bf16(ah, bl, acc, 0, 0, 0);
        acc = __builtin_amdgcn_mfma_f32_16x16x32_bf16(al, bh, acc, 0, 0, 0);
    }
#pragma unroll
    for (int r = 0; r < 4; ++r)
        h[(size_t)(m0 + quad * 4 + r) * OUT_CH + n0 + r15] = acc[r];
}

// ---------- fused gather-aggregate + minmax scale + L2 normalize ----------
// One wave per node. Lane l owns channels {2l, 2l+1}.
__global__ __launch_bounds__(256) void k_agg_fin(const float* __restrict__ h,
                                                 const float* __restrict__ dinv,
                                                 const int2* __restrict__ es,
                                                 const int* __restrict__ base,
                                                 const int* __restrict__ cnt,
                                                 const float* __restrict__ b,
                                                 float* __restrict__ out) {
    int node = (blockIdx.x * 256 + threadIdx.x) >> 6;
    int lane = threadIdx.x & 63;
    if (node >= N_NODES) return;

    float dn = dinv[node];
    // self-loop + bias
    float2 hv = ((const float2*)(h + (size_t)node * OUT_CH))[lane];
    float2 bv = ((const float2*)b)[lane];
    float w0 = dn * dn;
    float2 acc;
    acc.x = hv.x * w0 + bv.x;
    acc.y = hv.y * w0 + bv.y;

    int st = base[node];
    int d = cnt[node];
    for (int j0 = 0; j0 < d; j0 += 64) {
        int m = d - j0;
        if (m > 64) m = 64;
        int2 ew = make_int2(0, 0);
        if (lane < m) ew = es[st + j0 + lane];
        for (int j = 0; j < m; ++j) {
            int s = __shfl(ew.x, j, 64);
            float ws = __shfl(__int_as_float(ew.y), j, 64);
            float w = ws * dn;
            float2 g = ((const float2*)(h + (size_t)s * OUT_CH))[lane];
            acc.x += w * g.x;
            acc.y += w * g.y;
        }
    }

    // min-max scale
    float lmin = fminf(acc.x, acc.y), lmax = fmaxf(acc.x, acc.y);
#pragma unroll
    for (int m = 32; m; m >>= 1) {
        lmin = fminf(lmin, __shfl_xor(lmin, m, 64));
        lmax = fmaxf(lmax, __shfl_xor(lmax, m, 64));
    }
    float scale = 1.0f / (lmax - lmin);
    float zx = (acc.x - lmin) * scale;
    float zy = (acc.y - lmin) * scale;
    // L2 normalize
    float ss = zx * zx + zy * zy;
#pragma unroll
    for (int m = 32; m; m >>= 1) ss += __shfl_xor(ss, m, 64);
    float inv = 1.0f / fmaxf(sqrtf(ss), 1e-12f);
    float2 o;
    o.x = zx * inv;
    o.y = zy * inv;
    ((float2*)(out + (size_t)node * OUT_CH))[lane] = o;
}

extern "C" void kernel_launch(void* const* d_in, const int* in_sizes, int n_in,
                              void* d_out, int out_size, void* d_ws, size_t ws_size,
                              hipStream_t stream) {
    const float* x = (const float*)d_in[0];        // fp32 [N, 256]
    const int* ei = (const int*)d_in[1];           // int32 [2, E]
    const float* W = (const float*)d_in[2];        // fp32 [256, 128]
    const float* b = (const float*)d_in[3];        // fp32 [128]
    float* out = (float*)d_out;                    // fp32 [N, 128]

    char* ws = (char*)d_ws;
    size_t o = 0;
    auto alloc = [&](size_t bytes) { void* p = ws + o; o = (o + bytes + 255) & ~(size_t)255; return p; };
    float* dinv   = (float*)alloc((size_t)N_NODES * 4);
    int*   cnt    = (int*)  alloc((size_t)N_NODES * 4);
    int*   base   = (int*)  alloc((size_t)N_NODES * 4);
    int*   cursor = (int*)  alloc((size_t)N_NODES * 4);
    int*   bsum   = (int*)  alloc(512 * 4);
    unsigned short* wt_hi = (unsigned short*)alloc((size_t)IN_CH * OUT_CH * 2);
    unsigned short* wt_lo = (unsigned short*)alloc((size_t)IN_CH * OUT_CH * 2);
    float* h      = (float*)alloc((size_t)N_NODES * OUT_CH * 4);
    int2*  es     = (int2*) alloc((size_t)N_EDGES * 8);

    const int* rows = ei;
    const int* cols = ei + N_EDGES;

    // CSR build
    k_zero<<<NB, 256, 0, stream>>>(cnt);
    k_hist<<<(N_EDGES + 255) / 256, 256, 0, stream>>>(cols, cnt);
    k_scan1<<<NB, 256, 0, stream>>>(cnt, bsum);
    k_scan2<<<1, 512, 0, stream>>>(bsum);
    k_scan3<<<NB, 256, 0, stream>>>(cnt, bsum, base, cursor, dinv);
    k_sort_edges<<<(N_EDGES + 255) / 256, 256, 0, stream>>>(rows, cols, dinv, cursor, es);

    // GEMM
    k_prep_w<<<(IN_CH * OUT_CH + 255) / 256, 256, 0, stream>>>(W, wt_hi, wt_lo);
    k_gemm<<<12500, 256, 0, stream>>>(x, wt_hi, wt_lo, h);

    // fused aggregate + scale + normalize
    k_agg_fin<<<(N_NODES + 3) / 4, 256, 0, stream>>>(h, dinv, es, base, cnt, b, out);
}

// Round 4
// 465.900 us; speedup vs baseline: 6.7200x; 1.2976x over previous
//
#include <hip/hip_runtime.h>
#include <hip/hip_bf16.h>

#define N_NODES 100000
#define N_EDGES 1600000
#define IN_CH 256
#define OUT_CH 128
#define NB 391   // ceil(N_NODES/256)

#define GEMM_ROWS 32       // rows per block
#define LDS_STRIDE 260     // floats per staged row (256 + 4 pad)

typedef __attribute__((ext_vector_type(8))) short short8;
typedef __attribute__((ext_vector_type(4))) float floatx4;

union bfu { __hip_bfloat16 b; unsigned short u; };

__device__ inline unsigned short f2bf(float v) {
    bfu cv; cv.b = __float2bfloat16(v); return cv.u;
}
__device__ inline float bf2f(unsigned short u) {
    bfu cv; cv.u = u; return __bfloat162float(cv.b);
}

// ---------- CSR build: histogram ----------
__global__ void k_zero(int* cnt) {
    int i = blockIdx.x * 256 + threadIdx.x;
    if (i < N_NODES) cnt[i] = 0;
}

__global__ void k_hist(const int* __restrict__ cols, int* __restrict__ cnt) {
    int e = blockIdx.x * 256 + threadIdx.x;
    if (e < N_EDGES) atomicAdd(&cnt[cols[e]], 1);
}

// per-block sums of cnt
__global__ __launch_bounds__(256) void k_scan1(const int* __restrict__ cnt, int* __restrict__ bsum) {
    __shared__ int s[256];
    int t = threadIdx.x;
    int i = blockIdx.x * 256 + t;
    s[t] = (i < N_NODES) ? cnt[i] : 0;
    __syncthreads();
#pragma unroll
    for (int off = 128; off; off >>= 1) {
        if (t < off) s[t] += s[t + off];
        __syncthreads();
    }
    if (t == 0) bsum[blockIdx.x] = s[0];
}

// exclusive scan of the 391 block sums (single block)
__global__ __launch_bounds__(512) void k_scan2(int* bsum) {
    __shared__ int s[512];
    int t = threadIdx.x;
    int v = (t < NB) ? bsum[t] : 0;
    s[t] = v;
    __syncthreads();
    for (int off = 1; off < 512; off <<= 1) {
        int u = (t >= off) ? s[t - off] : 0;
        __syncthreads();
        s[t] += u;
        __syncthreads();
    }
    if (t < NB) bsum[t] = s[t] - v;   // exclusive
}

// per-block exclusive scan + block offset -> base, cursor; also dinv
__global__ __launch_bounds__(256) void k_scan3(const int* __restrict__ cnt,
                                               const int* __restrict__ bsum,
                                               int* __restrict__ base,
                                               int* __restrict__ cursor,
                                               float* __restrict__ dinv) {
    __shared__ int s[256];
    int t = threadIdx.x;
    int i = blockIdx.x * 256 + t;
    int v = (i < N_NODES) ? cnt[i] : 0;
    s[t] = v;
    __syncthreads();
    for (int off = 1; off < 256; off <<= 1) {
        int u = (t >= off) ? s[t - off] : 0;
        __syncthreads();
        s[t] += u;
        __syncthreads();
    }
    if (i < N_NODES) {
        int b = bsum[blockIdx.x] + s[t] - v;   // exclusive position
        base[i] = b;
        cursor[i] = b;
        dinv[i] = rsqrtf((float)(v + 1));      // self-loop included
    }
}

// scatter edges into CSR order, storing (src, dinv[src])
__global__ void k_sort_edges(const int* __restrict__ rows, const int* __restrict__ cols,
                             const float* __restrict__ dinv,
                             int* __restrict__ cursor, int2* __restrict__ es) {
    int e = blockIdx.x * 256 + threadIdx.x;
    if (e >= N_EDGES) return;
    int c = cols[e], r = rows[e];
    int pos = atomicAdd(&cursor[c], 1);
    es[pos] = make_int2(r, __float_as_int(dinv[r]));
}

// ---------- W (fp32, [256,128]) -> MFMA-fragment-packed bf16 hi/lo ----------
// wb[t][s][lane][j] = bf16(W[k][n]), k = s*32 + (lane>>4)*8 + j, n = t*16 + (lane&15)
// so a wave's B-fragment load is lane-contiguous 16 B.
__global__ void k_prep_w(const float* __restrict__ W,
                         unsigned short* __restrict__ wb_hi,
                         unsigned short* __restrict__ wb_lo) {
    int t = blockIdx.x * 256 + threadIdx.x;   // 0..32767
    if (t >= IN_CH * OUT_CH) return;
    int j = t & 7;
    int lane = (t >> 3) & 63;
    int s = (t >> 9) & 7;
    int nt = t >> 12;
    int k = s * 32 + (lane >> 4) * 8 + j;
    int n = nt * 16 + (lane & 15);
    float w = W[k * OUT_CH + n];
    unsigned short hi = f2bf(w);
    wb_hi[t] = hi;
    wb_lo[t] = f2bf(w - bf2f(hi));
}

// ---------- h = x @ W  (fp32 in via split-bf16 MFMA, fp32 out) ----------
// Block: 512 threads = 8 waves, tile 32 rows x 128 cols. Wave w owns n-tile w.
// x staged to LDS via global_load_lds (16B), rows padded to 260 floats.
__global__ __launch_bounds__(512) void k_gemm(const float* __restrict__ x,
                                              const unsigned short* __restrict__ wb_hi,
                                              const unsigned short* __restrict__ wb_lo,
                                              float* __restrict__ h) {
    __shared__ float xs[GEMM_ROWS * LDS_STRIDE];   // 33280 B
    int wv = threadIdx.x >> 6;        // 0..7 = n-tile
    int lane = threadIdx.x & 63;
    int row0 = blockIdx.x * GEMM_ROWS;

    // stage: wave wv stages rows wv*4 .. wv*4+3 (each row = 1 KB, one wave-load)
#pragma unroll
    for (int r = 0; r < 4; ++r) {
        int lr = wv * 4 + r;
        const float* src = x + (size_t)(row0 + lr) * IN_CH + lane * 4;
        __builtin_amdgcn_global_load_lds(
            (const __attribute__((address_space(1))) void*)src,
            (__attribute__((address_space(3))) void*)&xs[lr * LDS_STRIDE],
            16, 0, 0);
    }

    // B fragments: full K, hi+lo, packed lane-contiguous -> 16 coalesced 16B loads
    short8 Bh[8], Bl[8];
    const short8* bhp = (const short8*)wb_hi + (size_t)wv * 8 * 64 + lane;
    const short8* blp = (const short8*)wb_lo + (size_t)wv * 8 * 64 + lane;
#pragma unroll
    for (int s = 0; s < 8; ++s) {
        Bh[s] = bhp[s * 64];
        Bl[s] = blp[s * 64];
    }

    asm volatile("s_waitcnt vmcnt(0)" ::: "memory");
    __syncthreads();

    int r15 = lane & 15;
    int quad = lane >> 4;

    floatx4 acc[2];
#pragma unroll
    for (int ms = 0; ms < 2; ++ms) {
        acc[ms] = (floatx4){0.f, 0.f, 0.f, 0.f};
        const float* ap = xs + (ms * 16 + r15) * LDS_STRIDE + quad * 8;
#pragma unroll
        for (int s = 0; s < 8; ++s) {
            float4 v0 = *(const float4*)(ap + s * 32);
            float4 v1 = *(const float4*)(ap + s * 32 + 4);
            float xv[8] = {v0.x, v0.y, v0.z, v0.w, v1.x, v1.y, v1.z, v1.w};
            short8 ah, al;
#pragma unroll
            for (int j = 0; j < 8; ++j) {
                unsigned short hi = f2bf(xv[j]);
                ah[j] = (short)hi;
                al[j] = (short)f2bf(xv[j] - bf2f(hi));
            }
            acc[ms] = __builtin_amdgcn_mfma_f32_16x16x32_bf16(ah, Bh[s], acc[ms], 0, 0, 0);
            acc[ms] = __builtin_amdgcn_mfma_f32_16x16x32_bf16(ah, Bl[s], acc[ms], 0, 0, 0);
            acc[ms] = __builtin_amdgcn_mfma_f32_16x16x32_bf16(al, Bh[s], acc[ms], 0, 0, 0);
        }
    }

    // store: D row = quad*4 + r, col = r15 (within 16x16 tile)
#pragma unroll
    for (int ms = 0; ms < 2; ++ms)
#pragma unroll
        for (int r = 0; r < 4; ++r)
            h[(size_t)(row0 + ms * 16 + quad * 4 + r) * OUT_CH + wv * 16 + r15] = acc[ms][r];
}

// ---------- fused gather-aggregate + minmax scale + L2 normalize ----------
// One wave per node. Lane l owns channels {2l, 2l+1}.
__global__ __launch_bounds__(256) void k_agg_fin(const float* __restrict__ h,
                                                 const float* __restrict__ dinv,
                                                 const int2* __restrict__ es,
                                                 const int* __restrict__ base,
                                                 const int* __restrict__ cnt,
                                                 const float* __restrict__ b,
                                                 float* __restrict__ out) {
    int node = (blockIdx.x * 256 + threadIdx.x) >> 6;
    int lane = threadIdx.x & 63;
    if (node >= N_NODES) return;

    float dn = dinv[node];
    // self-loop + bias
    float2 hv = ((const float2*)(h + (size_t)node * OUT_CH))[lane];
    float2 bv = ((const float2*)b)[lane];
    float w0 = dn * dn;
    float2 acc;
    acc.x = hv.x * w0 + bv.x;
    acc.y = hv.y * w0 + bv.y;

    int st = base[node];
    int d = cnt[node];
    for (int j0 = 0; j0 < d; j0 += 64) {
        int m = d - j0;
        if (m > 64) m = 64;
        int2 ew = make_int2(0, 0);
        if (lane < m) ew = es[st + j0 + lane];
        for (int j = 0; j < m; ++j) {
            int s = __shfl(ew.x, j, 64);
            float ws = __shfl(__int_as_float(ew.y), j, 64);
            float w = ws * dn;
            float2 g = ((const float2*)(h + (size_t)s * OUT_CH))[lane];
            acc.x += w * g.x;
            acc.y += w * g.y;
        }
    }

    // min-max scale
    float lmin = fminf(acc.x, acc.y), lmax = fmaxf(acc.x, acc.y);
#pragma unroll
    for (int m = 32; m; m >>= 1) {
        lmin = fminf(lmin, __shfl_xor(lmin, m, 64));
        lmax = fmaxf(lmax, __shfl_xor(lmax, m, 64));
    }
    float scale = 1.0f / (lmax - lmin);
    float zx = (acc.x - lmin) * scale;
    float zy = (acc.y - lmin) * scale;
    // L2 normalize
    float ss = zx * zx + zy * zy;
#pragma unroll
    for (int m = 32; m; m >>= 1) ss += __shfl_xor(ss, m, 64);
    float inv = 1.0f / fmaxf(sqrtf(ss), 1e-12f);
    float2 o;
    o.x = zx * inv;
    o.y = zy * inv;
    ((float2*)(out + (size_t)node * OUT_CH))[lane] = o;
}

extern "C" void kernel_launch(void* const* d_in, const int* in_sizes, int n_in,
                              void* d_out, int out_size, void* d_ws, size_t ws_size,
                              hipStream_t stream) {
    const float* x = (const float*)d_in[0];        // fp32 [N, 256]
    const int* ei = (const int*)d_in[1];           // int32 [2, E]
    const float* W = (const float*)d_in[2];        // fp32 [256, 128]
    const float* b = (const float*)d_in[3];        // fp32 [128]
    float* out = (float*)d_out;                    // fp32 [N, 128]

    char* ws = (char*)d_ws;
    size_t o = 0;
    auto alloc = [&](size_t bytes) { void* p = ws + o; o = (o + bytes + 255) & ~(size_t)255; return p; };
    float* dinv   = (float*)alloc((size_t)N_NODES * 4);
    int*   cnt    = (int*)  alloc((size_t)N_NODES * 4);
    int*   base   = (int*)  alloc((size_t)N_NODES * 4);
    int*   cursor = (int*)  alloc((size_t)N_NODES * 4);
    int*   bsum   = (int*)  alloc(512 * 4);
    unsigned short* wb_hi = (unsigned short*)alloc((size_t)IN_CH * OUT_CH * 2);
    unsigned short* wb_lo = (unsigned short*)alloc((size_t)IN_CH * OUT_CH * 2);
    float* h      = (float*)alloc((size_t)N_NODES * OUT_CH * 4);
    int2*  es     = (int2*) alloc((size_t)N_EDGES * 8);

    const int* rows = ei;
    const int* cols = ei + N_EDGES;

    // CSR build
    k_zero<<<NB, 256, 0, stream>>>(cnt);
    k_hist<<<(N_EDGES + 255) / 256, 256, 0, stream>>>(cols, cnt);
    k_scan1<<<NB, 256, 0, stream>>>(cnt, bsum);
    k_scan2<<<1, 512, 0, stream>>>(bsum);
    k_scan3<<<NB, 256, 0, stream>>>(cnt, bsum, base, cursor, dinv);
    k_sort_edges<<<(N_EDGES + 255) / 256, 256, 0, stream>>>(rows, cols, dinv, cursor, es);

    // GEMM
    k_prep_w<<<(IN_CH * OUT_CH + 255) / 256, 256, 0, stream>>>(W, wb_hi, wb_lo);
    k_gemm<<<N_NODES / GEMM_ROWS, 512, 0, stream>>>(x, wb_hi, wb_lo, h);

    // fused aggregate + scale + normalize
    k_agg_fin<<<(N_NODES + 3) / 4, 256, 0, stream>>>(h, dinv, es, base, cnt, b, out);
}

// Round 5
// 462.321 us; speedup vs baseline: 6.7720x; 1.0077x over previous
//
#include <hip/hip_runtime.h>
#include <hip/hip_bf16.h>

#define N_NODES 100000
#define N_EDGES 1600000
#define IN_CH 256
#define OUT_CH 128
#define NB 391   // ceil(N_NODES/256)

#define GEMM_ROWS 32       // rows per block
#define LDS_STRIDE 260     // floats per staged row (256 + 4 pad)

typedef __attribute__((ext_vector_type(8))) short short8;
typedef __attribute__((ext_vector_type(4))) float floatx4;

union bfu { __hip_bfloat16 b; unsigned short u; };

__device__ inline unsigned short f2bf(float v) {
    bfu cv; cv.b = __float2bfloat16(v); return cv.u;
}
__device__ inline float bf2f(unsigned short u) {
    bfu cv; cv.u = u; return __bfloat162float(cv.b);
}

// ---------- CSR build: histogram ----------
__global__ void k_zero(int* cnt) {
    int i = blockIdx.x * 256 + threadIdx.x;
    if (i < N_NODES) cnt[i] = 0;
}

__global__ void k_hist(const int* __restrict__ cols, int* __restrict__ cnt) {
    int e = blockIdx.x * 256 + threadIdx.x;
    if (e < N_EDGES) atomicAdd(&cnt[cols[e]], 1);
}

// per-block sums of cnt
__global__ __launch_bounds__(256) void k_scan1(const int* __restrict__ cnt, int* __restrict__ bsum) {
    __shared__ int s[256];
    int t = threadIdx.x;
    int i = blockIdx.x * 256 + t;
    s[t] = (i < N_NODES) ? cnt[i] : 0;
    __syncthreads();
#pragma unroll
    for (int off = 128; off; off >>= 1) {
        if (t < off) s[t] += s[t + off];
        __syncthreads();
    }
    if (t == 0) bsum[blockIdx.x] = s[0];
}

// exclusive scan of the 391 block sums (single block)
__global__ __launch_bounds__(512) void k_scan2(int* bsum) {
    __shared__ int s[512];
    int t = threadIdx.x;
    int v = (t < NB) ? bsum[t] : 0;
    s[t] = v;
    __syncthreads();
    for (int off = 1; off < 512; off <<= 1) {
        int u = (t >= off) ? s[t - off] : 0;
        __syncthreads();
        s[t] += u;
        __syncthreads();
    }
    if (t < NB) bsum[t] = s[t] - v;   // exclusive
}

// per-block exclusive scan + block offset -> base, cursor; also dinv
__global__ __launch_bounds__(256) void k_scan3(const int* __restrict__ cnt,
                                               const int* __restrict__ bsum,
                                               int* __restrict__ base,
                                               int* __restrict__ cursor,
                                               float* __restrict__ dinv) {
    __shared__ int s[256];
    int t = threadIdx.x;
    int i = blockIdx.x * 256 + t;
    int v = (i < N_NODES) ? cnt[i] : 0;
    s[t] = v;
    __syncthreads();
    for (int off = 1; off < 256; off <<= 1) {
        int u = (t >= off) ? s[t - off] : 0;
        __syncthreads();
        s[t] += u;
        __syncthreads();
    }
    if (i < N_NODES) {
        int b = bsum[blockIdx.x] + s[t] - v;   // exclusive position
        base[i] = b;
        cursor[i] = b;
        dinv[i] = rsqrtf((float)(v + 1));      // self-loop included
    }
}

// scatter edges into CSR order, storing (src, dinv[src])
__global__ void k_sort_edges(const int* __restrict__ rows, const int* __restrict__ cols,
                             const float* __restrict__ dinv,
                             int* __restrict__ cursor, int2* __restrict__ es) {
    int e = blockIdx.x * 256 + threadIdx.x;
    if (e >= N_EDGES) return;
    int c = cols[e], r = rows[e];
    int pos = atomicAdd(&cursor[c], 1);
    es[pos] = make_int2(r, __float_as_int(dinv[r]));
}

// ---------- W (fp32, [256,128]) -> MFMA-fragment-packed bf16 hi/lo ----------
__global__ void k_prep_w(const float* __restrict__ W,
                         unsigned short* __restrict__ wb_hi,
                         unsigned short* __restrict__ wb_lo) {
    int t = blockIdx.x * 256 + threadIdx.x;   // 0..32767
    if (t >= IN_CH * OUT_CH) return;
    int j = t & 7;
    int lane = (t >> 3) & 63;
    int s = (t >> 9) & 7;
    int nt = t >> 12;
    int k = s * 32 + (lane >> 4) * 8 + j;
    int n = nt * 16 + (lane & 15);
    float w = W[k * OUT_CH + n];
    unsigned short hi = f2bf(w);
    wb_hi[t] = hi;
    wb_lo[t] = f2bf(w - bf2f(hi));
}

// ---------- h = x @ W  (fp32 in via split-bf16 MFMA; fp32 h + bf16 hb out) ----------
__global__ __launch_bounds__(512) void k_gemm(const float* __restrict__ x,
                                              const unsigned short* __restrict__ wb_hi,
                                              const unsigned short* __restrict__ wb_lo,
                                              float* __restrict__ h,
                                              unsigned short* __restrict__ hb) {
    __shared__ float xs[GEMM_ROWS * LDS_STRIDE];   // 33280 B
    int wv = threadIdx.x >> 6;        // 0..7 = n-tile
    int lane = threadIdx.x & 63;
    int row0 = blockIdx.x * GEMM_ROWS;

#pragma unroll
    for (int r = 0; r < 4; ++r) {
        int lr = wv * 4 + r;
        const float* src = x + (size_t)(row0 + lr) * IN_CH + lane * 4;
        __builtin_amdgcn_global_load_lds(
            (const __attribute__((address_space(1))) void*)src,
            (__attribute__((address_space(3))) void*)&xs[lr * LDS_STRIDE],
            16, 0, 0);
    }

    short8 Bh[8], Bl[8];
    const short8* bhp = (const short8*)wb_hi + (size_t)wv * 8 * 64 + lane;
    const short8* blp = (const short8*)wb_lo + (size_t)wv * 8 * 64 + lane;
#pragma unroll
    for (int s = 0; s < 8; ++s) {
        Bh[s] = bhp[s * 64];
        Bl[s] = blp[s * 64];
    }

    asm volatile("s_waitcnt vmcnt(0)" ::: "memory");
    __syncthreads();

    int r15 = lane & 15;
    int quad = lane >> 4;

    floatx4 acc[2];
#pragma unroll
    for (int ms = 0; ms < 2; ++ms) {
        acc[ms] = (floatx4){0.f, 0.f, 0.f, 0.f};
        const float* ap = xs + (ms * 16 + r15) * LDS_STRIDE + quad * 8;
#pragma unroll
        for (int s = 0; s < 8; ++s) {
            float4 v0 = *(const float4*)(ap + s * 32);
            float4 v1 = *(const float4*)(ap + s * 32 + 4);
            float xv[8] = {v0.x, v0.y, v0.z, v0.w, v1.x, v1.y, v1.z, v1.w};
            short8 ah, al;
#pragma unroll
            for (int j = 0; j < 8; ++j) {
                unsigned short hi = f2bf(xv[j]);
                ah[j] = (short)hi;
                al[j] = (short)f2bf(xv[j] - bf2f(hi));
            }
            acc[ms] = __builtin_amdgcn_mfma_f32_16x16x32_bf16(ah, Bh[s], acc[ms], 0, 0, 0);
            acc[ms] = __builtin_amdgcn_mfma_f32_16x16x32_bf16(ah, Bl[s], acc[ms], 0, 0, 0);
            acc[ms] = __builtin_amdgcn_mfma_f32_16x16x32_bf16(al, Bh[s], acc[ms], 0, 0, 0);
        }
    }

    // store: D row = quad*4 + r, col = r15 (within 16x16 tile); fp32 + bf16 copies
#pragma unroll
    for (int ms = 0; ms < 2; ++ms)
#pragma unroll
        for (int r = 0; r < 4; ++r) {
            size_t idx = (size_t)(row0 + ms * 16 + quad * 4 + r) * OUT_CH + wv * 16 + r15;
            h[idx] = acc[ms][r];
            hb[idx] = f2bf(acc[ms][r]);
        }
}

// ---------- fused gather-aggregate + minmax scale + L2 normalize ----------
// One wave per node. Lane l owns channels {2l, 2l+1}. Edge gathers read bf16 hb.
__global__ __launch_bounds__(256) void k_agg_fin(const float* __restrict__ h,
                                                 const unsigned short* __restrict__ hb,
                                                 const float* __restrict__ dinv,
                                                 const int2* __restrict__ es,
                                                 const int* __restrict__ base,
                                                 const int* __restrict__ cnt,
                                                 const float* __restrict__ b,
                                                 float* __restrict__ out) {
    int node = (blockIdx.x * 256 + threadIdx.x) >> 6;
    int lane = threadIdx.x & 63;
    if (node >= N_NODES) return;

    float dn = dinv[node];
    // self-loop (fp32) + bias
    float2 hv = ((const float2*)(h + (size_t)node * OUT_CH))[lane];
    float2 bv = ((const float2*)b)[lane];
    float w0 = dn * dn;
    float2 acc;
    acc.x = hv.x * w0 + bv.x;
    acc.y = hv.y * w0 + bv.y;

    int st = base[node];
    int d = cnt[node];
    for (int j0 = 0; j0 < d; j0 += 64) {
        int m = d - j0;
        if (m > 64) m = 64;
        int2 ew = make_int2(0, 0);
        if (lane < m) ew = es[st + j0 + lane];
        for (int j = 0; j < m; ++j) {
            int s = __shfl(ew.x, j, 64);
            float ws = __shfl(__int_as_float(ew.y), j, 64);
            float w = ws * dn;
            ushort2 g = ((const ushort2*)(hb + (size_t)s * OUT_CH))[lane];
            acc.x += w * bf2f(g.x);
            acc.y += w * bf2f(g.y);
        }
    }

    // min-max scale
    float lmin = fminf(acc.x, acc.y), lmax = fmaxf(acc.x, acc.y);
#pragma unroll
    for (int m = 32; m; m >>= 1) {
        lmin = fminf(lmin, __shfl_xor(lmin, m, 64));
        lmax = fmaxf(lmax, __shfl_xor(lmax, m, 64));
    }
    float scale = 1.0f / (lmax - lmin);
    float zx = (acc.x - lmin) * scale;
    float zy = (acc.y - lmin) * scale;
    // L2 normalize
    float ss = zx * zx + zy * zy;
#pragma unroll
    for (int m = 32; m; m >>= 1) ss += __shfl_xor(ss, m, 64);
    float inv = 1.0f / fmaxf(sqrtf(ss), 1e-12f);
    float2 o;
    o.x = zx * inv;
    o.y = zy * inv;
    ((float2*)(out + (size_t)node * OUT_CH))[lane] = o;
}

extern "C" void kernel_launch(void* const* d_in, const int* in_sizes, int n_in,
                              void* d_out, int out_size, void* d_ws, size_t ws_size,
                              hipStream_t stream) {
    const float* x = (const float*)d_in[0];        // fp32 [N, 256]
    const int* ei = (const int*)d_in[1];           // int32 [2, E]
    const float* W = (const float*)d_in[2];        // fp32 [256, 128]
    const float* b = (const float*)d_in[3];        // fp32 [128]
    float* out = (float*)d_out;                    // fp32 [N, 128]

    char* ws = (char*)d_ws;
    size_t o = 0;
    auto alloc = [&](size_t bytes) { void* p = ws + o; o = (o + bytes + 255) & ~(size_t)255; return p; };
    float* dinv   = (float*)alloc((size_t)N_NODES * 4);
    int*   cnt    = (int*)  alloc((size_t)N_NODES * 4);
    int*   base   = (int*)  alloc((size_t)N_NODES * 4);
    int*   cursor = (int*)  alloc((size_t)N_NODES * 4);
    int*   bsum   = (int*)  alloc(512 * 4);
    unsigned short* wb_hi = (unsigned short*)alloc((size_t)IN_CH * OUT_CH * 2);
    unsigned short* wb_lo = (unsigned short*)alloc((size_t)IN_CH * OUT_CH * 2);
    float* h      = (float*)alloc((size_t)N_NODES * OUT_CH * 4);
    unsigned short* hb = (unsigned short*)alloc((size_t)N_NODES * OUT_CH * 2);
    int2*  es     = (int2*) alloc((size_t)N_EDGES * 8);

    const int* rows = ei;
    const int* cols = ei + N_EDGES;

    // CSR build
    k_zero<<<NB, 256, 0, stream>>>(cnt);
    k_hist<<<(N_EDGES + 255) / 256, 256, 0, stream>>>(cols, cnt);
    k_scan1<<<NB, 256, 0, stream>>>(cnt, bsum);
    k_scan2<<<1, 512, 0, stream>>>(bsum);
    k_scan3<<<NB, 256, 0, stream>>>(cnt, bsum, base, cursor, dinv);
    k_sort_edges<<<(N_EDGES + 255) / 256, 256, 0, stream>>>(rows, cols, dinv, cursor, es);

    // GEMM
    k_prep_w<<<(IN_CH * OUT_CH + 255) / 256, 256, 0, stream>>>(W, wb_hi, wb_lo);
    k_gemm<<<N_NODES / GEMM_ROWS, 512, 0, stream>>>(x, wb_hi, wb_lo, h, hb);

    // fused aggregate + scale + normalize
    k_agg_fin<<<(N_NODES + 3) / 4, 256, 0, stream>>>(h, hb, dinv, es, base, cnt, b, out);
}

// Round 6
// 450.430 us; speedup vs baseline: 6.9508x; 1.0264x over previous
//
#include <hip/hip_runtime.h>
#include <hip/hip_bf16.h>

#define N_NODES 100000
#define N_EDGES 1600000
#define IN_CH 256
#define OUT_CH 128
#define NB 391   // ceil(N_NODES/256)

#define GEMM_ROWS 32       // rows per block
#define LDS_STRIDE 260     // floats per staged row (256 + 4 pad)

typedef __attribute__((ext_vector_type(8))) short short8;
typedef __attribute__((ext_vector_type(4))) float floatx4;

union bfu { __hip_bfloat16 b; unsigned short u; };

__device__ inline unsigned short f2bf(float v) {
    bfu cv; cv.b = __float2bfloat16(v); return cv.u;
}
__device__ inline float bf2f(unsigned short u) {
    bfu cv; cv.u = u; return __bfloat162float(cv.b);
}

// ---------- CSR build: histogram ----------
__global__ void k_zero(int* cnt) {
    int i = blockIdx.x * 256 + threadIdx.x;
    if (i < N_NODES) cnt[i] = 0;
}

__global__ void k_hist(const int* __restrict__ cols, int* __restrict__ cnt) {
    int e = blockIdx.x * 256 + threadIdx.x;
    if (e < N_EDGES) atomicAdd(&cnt[cols[e]], 1);
}

// per-block sums of cnt
__global__ __launch_bounds__(256) void k_scan1(const int* __restrict__ cnt, int* __restrict__ bsum) {
    __shared__ int s[256];
    int t = threadIdx.x;
    int i = blockIdx.x * 256 + t;
    s[t] = (i < N_NODES) ? cnt[i] : 0;
    __syncthreads();
#pragma unroll
    for (int off = 128; off; off >>= 1) {
        if (t < off) s[t] += s[t + off];
        __syncthreads();
    }
    if (t == 0) bsum[blockIdx.x] = s[0];
}

// exclusive scan of the 391 block sums (single block)
__global__ __launch_bounds__(512) void k_scan2(int* bsum) {
    __shared__ int s[512];
    int t = threadIdx.x;
    int v = (t < NB) ? bsum[t] : 0;
    s[t] = v;
    __syncthreads();
    for (int off = 1; off < 512; off <<= 1) {
        int u = (t >= off) ? s[t - off] : 0;
        __syncthreads();
        s[t] += u;
        __syncthreads();
    }
    if (t < NB) bsum[t] = s[t] - v;   // exclusive
}

// per-block exclusive scan + block offset -> base, cursor; also dinv
__global__ __launch_bounds__(256) void k_scan3(const int* __restrict__ cnt,
                                               const int* __restrict__ bsum,
                                               int* __restrict__ base,
                                               int* __restrict__ cursor,
                                               float* __restrict__ dinv) {
    __shared__ int s[256];
    int t = threadIdx.x;
    int i = blockIdx.x * 256 + t;
    int v = (i < N_NODES) ? cnt[i] : 0;
    s[t] = v;
    __syncthreads();
    for (int off = 1; off < 256; off <<= 1) {
        int u = (t >= off) ? s[t - off] : 0;
        __syncthreads();
        s[t] += u;
        __syncthreads();
    }
    if (i < N_NODES) {
        int b = bsum[blockIdx.x] + s[t] - v;   // exclusive position
        base[i] = b;
        cursor[i] = b;
        dinv[i] = rsqrtf((float)(v + 1));      // self-loop included
    }
}

// scatter edges into CSR order, storing src only (4 B/edge)
__global__ void k_sort_edges(const int* __restrict__ rows, const int* __restrict__ cols,
                             int* __restrict__ cursor, int* __restrict__ es) {
    int e = blockIdx.x * 256 + threadIdx.x;
    if (e >= N_EDGES) return;
    int c = cols[e], r = rows[e];
    int pos = atomicAdd(&cursor[c], 1);
    es[pos] = r;
}

// ---------- W (fp32, [256,128]) -> MFMA-fragment-packed bf16 hi/lo ----------
__global__ void k_prep_w(const float* __restrict__ W,
                         unsigned short* __restrict__ wb_hi,
                         unsigned short* __restrict__ wb_lo) {
    int t = blockIdx.x * 256 + threadIdx.x;   // 0..32767
    if (t >= IN_CH * OUT_CH) return;
    int j = t & 7;
    int lane = (t >> 3) & 63;
    int s = (t >> 9) & 7;
    int nt = t >> 12;
    int k = s * 32 + (lane >> 4) * 8 + j;
    int n = nt * 16 + (lane & 15);
    float w = W[k * OUT_CH + n];
    unsigned short hi = f2bf(w);
    wb_hi[t] = hi;
    wb_lo[t] = f2bf(w - bf2f(hi));
}

// ---------- h = x @ W  (fp32 in via split-bf16 MFMA) ----------
// Outputs: h (fp32, unscaled, for self-loop) and hbs (bf16, pre-scaled by dinv[row],
// for edge gathers).
__global__ __launch_bounds__(512) void k_gemm(const float* __restrict__ x,
                                              const unsigned short* __restrict__ wb_hi,
                                              const unsigned short* __restrict__ wb_lo,
                                              const float* __restrict__ dinv,
                                              float* __restrict__ h,
                                              unsigned short* __restrict__ hbs) {
    __shared__ float xs[GEMM_ROWS * LDS_STRIDE];   // 33280 B
    int wv = threadIdx.x >> 6;        // 0..7 = n-tile
    int lane = threadIdx.x & 63;
    int row0 = blockIdx.x * GEMM_ROWS;

#pragma unroll
    for (int r = 0; r < 4; ++r) {
        int lr = wv * 4 + r;
        const float* src = x + (size_t)(row0 + lr) * IN_CH + lane * 4;
        __builtin_amdgcn_global_load_lds(
            (const __attribute__((address_space(1))) void*)src,
            (__attribute__((address_space(3))) void*)&xs[lr * LDS_STRIDE],
            16, 0, 0);
    }

    short8 Bh[8], Bl[8];
    const short8* bhp = (const short8*)wb_hi + (size_t)wv * 8 * 64 + lane;
    const short8* blp = (const short8*)wb_lo + (size_t)wv * 8 * 64 + lane;
#pragma unroll
    for (int s = 0; s < 8; ++s) {
        Bh[s] = bhp[s * 64];
        Bl[s] = blp[s * 64];
    }

    asm volatile("s_waitcnt vmcnt(0)" ::: "memory");
    __syncthreads();

    int r15 = lane & 15;
    int quad = lane >> 4;

    floatx4 acc[2];
#pragma unroll
    for (int ms = 0; ms < 2; ++ms) {
        acc[ms] = (floatx4){0.f, 0.f, 0.f, 0.f};
        const float* ap = xs + (ms * 16 + r15) * LDS_STRIDE + quad * 8;
#pragma unroll
        for (int s = 0; s < 8; ++s) {
            float4 v0 = *(const float4*)(ap + s * 32);
            float4 v1 = *(const float4*)(ap + s * 32 + 4);
            float xv[8] = {v0.x, v0.y, v0.z, v0.w, v1.x, v1.y, v1.z, v1.w};
            short8 ah, al;
#pragma unroll
            for (int j = 0; j < 8; ++j) {
                unsigned short hi = f2bf(xv[j]);
                ah[j] = (short)hi;
                al[j] = (short)f2bf(xv[j] - bf2f(hi));
            }
            acc[ms] = __builtin_amdgcn_mfma_f32_16x16x32_bf16(ah, Bh[s], acc[ms], 0, 0, 0);
            acc[ms] = __builtin_amdgcn_mfma_f32_16x16x32_bf16(ah, Bl[s], acc[ms], 0, 0, 0);
            acc[ms] = __builtin_amdgcn_mfma_f32_16x16x32_bf16(al, Bh[s], acc[ms], 0, 0, 0);
        }
    }

    // store: D row = quad*4 + r, col = r15; fp32 unscaled + bf16 dinv-scaled
#pragma unroll
    for (int ms = 0; ms < 2; ++ms)
#pragma unroll
        for (int r = 0; r < 4; ++r) {
            int row = row0 + ms * 16 + quad * 4 + r;
            size_t idx = (size_t)row * OUT_CH + wv * 16 + r15;
            float v = acc[ms][r];
            h[idx] = v;
            hbs[idx] = f2bf(v * dinv[row]);
        }
}

// ---------- fused gather-aggregate + minmax scale + L2 normalize ----------
// One wave per node. Lane l owns channels {2l, 2l+1}.
// Edge stream scalarized (SGPR base + lane*4 offset); rows pre-scaled by dinv[src].
__global__ __launch_bounds__(256) void k_agg_fin(const float* __restrict__ h,
                                                 const unsigned short* __restrict__ hbs,
                                                 const float* __restrict__ dinv,
                                                 const int* __restrict__ es,
                                                 const int* __restrict__ base,
                                                 const int* __restrict__ cnt,
                                                 const float* __restrict__ b,
                                                 float* __restrict__ out) {
    int node = (blockIdx.x * 256 + threadIdx.x) >> 6;   // wave-uniform
    int lane = threadIdx.x & 63;
    if (node >= N_NODES) return;

    float dn = dinv[node];
    float2 hv = ((const float2*)(h + (size_t)node * OUT_CH))[lane];
    float2 bv = ((const float2*)b)[lane];

    int st = __builtin_amdgcn_readfirstlane(base[node]);
    int d  = __builtin_amdgcn_readfirstlane(cnt[node]);
    const int* ep = es + st;

    float ex = 0.f, ey = 0.f;   // edge sums of pre-scaled rows
    int j = 0;
    for (; j + 4 <= d; j += 4) {
        int s0 = __builtin_amdgcn_readfirstlane(ep[j + 0]);
        int s1 = __builtin_amdgcn_readfirstlane(ep[j + 1]);
        int s2 = __builtin_amdgcn_readfirstlane(ep[j + 2]);
        int s3 = __builtin_amdgcn_readfirstlane(ep[j + 3]);
        unsigned g0 = ((const unsigned*)(hbs + (size_t)s0 * OUT_CH))[lane];
        unsigned g1 = ((const unsigned*)(hbs + (size_t)s1 * OUT_CH))[lane];
        unsigned g2 = ((const unsigned*)(hbs + (size_t)s2 * OUT_CH))[lane];
        unsigned g3 = ((const unsigned*)(hbs + (size_t)s3 * OUT_CH))[lane];
        ex += __uint_as_float(g0 << 16);
        ey += __uint_as_float(g0 & 0xffff0000u);
        ex += __uint_as_float(g1 << 16);
        ey += __uint_as_float(g1 & 0xffff0000u);
        ex += __uint_as_float(g2 << 16);
        ey += __uint_as_float(g2 & 0xffff0000u);
        ex += __uint_as_float(g3 << 16);
        ey += __uint_as_float(g3 & 0xffff0000u);
    }
    for (; j < d; ++j) {
        int s0 = __builtin_amdgcn_readfirstlane(ep[j]);
        unsigned g0 = ((const unsigned*)(hbs + (size_t)s0 * OUT_CH))[lane];
        ex += __uint_as_float(g0 << 16);
        ey += __uint_as_float(g0 & 0xffff0000u);
    }

    float w0 = dn * dn;
    float2 acc;
    acc.x = hv.x * w0 + bv.x + dn * ex;
    acc.y = hv.y * w0 + bv.y + dn * ey;

    // min-max scale
    float lmin = fminf(acc.x, acc.y), lmax = fmaxf(acc.x, acc.y);
#pragma unroll
    for (int m = 32; m; m >>= 1) {
        lmin = fminf(lmin, __shfl_xor(lmin, m, 64));
        lmax = fmaxf(lmax, __shfl_xor(lmax, m, 64));
    }
    float scale = 1.0f / (lmax - lmin);
    float zx = (acc.x - lmin) * scale;
    float zy = (acc.y - lmin) * scale;
    // L2 normalize
    float ss = zx * zx + zy * zy;
#pragma unroll
    for (int m = 32; m; m >>= 1) ss += __shfl_xor(ss, m, 64);
    float inv = 1.0f / fmaxf(sqrtf(ss), 1e-12f);
    float2 o;
    o.x = zx * inv;
    o.y = zy * inv;
    ((float2*)(out + (size_t)node * OUT_CH))[lane] = o;
}

extern "C" void kernel_launch(void* const* d_in, const int* in_sizes, int n_in,
                              void* d_out, int out_size, void* d_ws, size_t ws_size,
                              hipStream_t stream) {
    const float* x = (const float*)d_in[0];        // fp32 [N, 256]
    const int* ei = (const int*)d_in[1];           // int32 [2, E]
    const float* W = (const float*)d_in[2];        // fp32 [256, 128]
    const float* b = (const float*)d_in[3];        // fp32 [128]
    float* out = (float*)d_out;                    // fp32 [N, 128]

    char* ws = (char*)d_ws;
    size_t o = 0;
    auto alloc = [&](size_t bytes) { void* p = ws + o; o = (o + bytes + 255) & ~(size_t)255; return p; };
    float* dinv   = (float*)alloc((size_t)N_NODES * 4);
    int*   cnt    = (int*)  alloc((size_t)N_NODES * 4);
    int*   base   = (int*)  alloc((size_t)N_NODES * 4);
    int*   cursor = (int*)  alloc((size_t)N_NODES * 4);
    int*   bsum   = (int*)  alloc(512 * 4);
    unsigned short* wb_hi = (unsigned short*)alloc((size_t)IN_CH * OUT_CH * 2);
    unsigned short* wb_lo = (unsigned short*)alloc((size_t)IN_CH * OUT_CH * 2);
    float* h      = (float*)alloc((size_t)N_NODES * OUT_CH * 4);
    unsigned short* hbs = (unsigned short*)alloc((size_t)N_NODES * OUT_CH * 2);
    int*   es     = (int*)  alloc((size_t)N_EDGES * 4);

    const int* rows = ei;
    const int* cols = ei + N_EDGES;

    // CSR build
    k_zero<<<NB, 256, 0, stream>>>(cnt);
    k_hist<<<(N_EDGES + 255) / 256, 256, 0, stream>>>(cols, cnt);
    k_scan1<<<NB, 256, 0, stream>>>(cnt, bsum);
    k_scan2<<<1, 512, 0, stream>>>(bsum);
    k_scan3<<<NB, 256, 0, stream>>>(cnt, bsum, base, cursor, dinv);
    k_sort_edges<<<(N_EDGES + 255) / 256, 256, 0, stream>>>(rows, cols, cursor, es);

    // GEMM
    k_prep_w<<<(IN_CH * OUT_CH + 255) / 256, 256, 0, stream>>>(W, wb_hi, wb_lo);
    k_gemm<<<N_NODES / GEMM_ROWS, 512, 0, stream>>>(x, wb_hi, wb_lo, dinv, h, hbs);

    // fused aggregate + scale + normalize
    k_agg_fin<<<(N_NODES + 3) / 4, 256, 0, stream>>>(h, hbs, dinv, es, base, cnt, b, out);
}

// Round 7
// 334.313 us; speedup vs baseline: 9.3650x; 1.3473x over previous
//
#include <hip/hip_runtime.h>
#include <hip/hip_bf16.h>

#define N_NODES 100000
#define N_EDGES 1600000
#define IN_CH 256
#define OUT_CH 128

#define BSZ 512            // nodes per bucket (power of 2)
#define NBUCK 196          // ceil(N_NODES / BSZ)
#define CHH 6400           // edges per block, pass-A histogram
#define CSC 8192           // edges per block, pass-A scatter

#define GEMM_ROWS 32       // rows per block
#define LDS_STRIDE 260     // floats per staged row (256 + 4 pad)

typedef __attribute__((ext_vector_type(8))) short short8;
typedef __attribute__((ext_vector_type(4))) float floatx4;

union bfu { __hip_bfloat16 b; unsigned short u; };

__device__ inline unsigned short f2bf(float v) {
    bfu cv; cv.b = __float2bfloat16(v); return cv.u;
}
__device__ inline float bf2f(unsigned short u) {
    bfu cv; cv.u = u; return __bfloat162float(cv.b);
}

// ---------- pass A: coarse bucket partition (bucket = dst >> 9) ----------
__global__ __launch_bounds__(256) void pa_zero(int* bhist) {
    int t = threadIdx.x;
    if (t < NBUCK) bhist[t] = 0;
}

__global__ __launch_bounds__(256) void pa_hist(const int* __restrict__ cols,
                                               int* __restrict__ bhist) {
    __shared__ int lh[NBUCK];
    int t = threadIdx.x;
    if (t < NBUCK) lh[t] = 0;
    __syncthreads();
    int s0 = blockIdx.x * CHH;
    int e1 = min(N_EDGES, s0 + CHH);
    for (int i = s0 + t; i < e1; i += 256) atomicAdd(&lh[cols[i] >> 9], 1);
    __syncthreads();
    if (t < NBUCK && lh[t]) atomicAdd(&bhist[t], lh[t]);
}

__global__ __launch_bounds__(256) void pa_scan(const int* __restrict__ bhist,
                                               int* __restrict__ bbase,
                                               int* __restrict__ bcursor) {
    __shared__ int s[256];
    int t = threadIdx.x;
    int v = (t < NBUCK) ? bhist[t] : 0;
    s[t] = v;
    __syncthreads();
    for (int off = 1; off < 256; off <<= 1) {
        int u = (t >= off) ? s[t - off] : 0;
        __syncthreads();
        s[t] += u;
        __syncthreads();
    }
    if (t < NBUCK) {
        int e = s[t] - v;   // exclusive
        bbase[t] = e;
        bcursor[t] = e;
    }
}

// per-block LDS count -> one reservation per bucket -> run-contiguous writes
__global__ __launch_bounds__(256) void pa_scatter(const int* __restrict__ rows,
                                                  const int* __restrict__ cols,
                                                  int* __restrict__ bcursor,
                                                  unsigned* __restrict__ ebuf) {
    __shared__ int lcnt[NBUCK];
    __shared__ int lbase[NBUCK];
    int t = threadIdx.x;
    if (t < NBUCK) lcnt[t] = 0;
    __syncthreads();
    int s0 = blockIdx.x * CSC;
    int e1 = min(N_EDGES, s0 + CSC);
    for (int i = s0 + t; i < e1; i += 256) atomicAdd(&lcnt[cols[i] >> 9], 1);
    __syncthreads();
    if (t < NBUCK) {
        int c = lcnt[t];
        lbase[t] = c ? atomicAdd(&bcursor[t], c) : 0;
        lcnt[t] = 0;
    }
    __syncthreads();
    for (int i = s0 + t; i < e1; i += 256) {
        int c = cols[i], r = rows[i];
        int bk = c >> 9;
        int rank = atomicAdd(&lcnt[bk], 1);
        ebuf[lbase[bk] + rank] = ((unsigned)(c & (BSZ - 1)) << 17) | (unsigned)r;
    }
}

// ---------- pass B: per-bucket fine sort + cnt/base/dinv, all in LDS ----------
__global__ __launch_bounds__(256) void pb_build(const unsigned* __restrict__ ebuf,
                                                const int* __restrict__ bhist,
                                                const int* __restrict__ bbase,
                                                int* __restrict__ cnt,
                                                int* __restrict__ base,
                                                float* __restrict__ dinv,
                                                int* __restrict__ es) {
    __shared__ int nh[BSZ];
    __shared__ int sc[BSZ];
    __shared__ int lcur[BSZ];
    int t = threadIdx.x;
    int bk = blockIdx.x;
    int bb = bbase[bk];
    int bc = bhist[bk];
    nh[t] = 0; nh[t + 256] = 0;
    lcur[t] = 0; lcur[t + 256] = 0;
    __syncthreads();
    for (int i = t; i < bc; i += 256) atomicAdd(&nh[ebuf[bb + i] >> 17], 1);
    __syncthreads();
    sc[t] = nh[t]; sc[t + 256] = nh[t + 256];
    __syncthreads();
    for (int off = 1; off < BSZ; off <<= 1) {
        int v0 = (t >= off) ? sc[t - off] : 0;
        int i1 = t + 256;
        int v1 = (i1 >= off) ? sc[i1 - off] : 0;
        __syncthreads();
        sc[t] += v0; sc[i1] += v1;
        __syncthreads();
    }
#pragma unroll
    for (int q = 0; q < 2; ++q) {
        int dl = t + q * 256;
        int node = bk * BSZ + dl;
        if (node < N_NODES) {
            int c = nh[dl];
            cnt[node] = c;
            base[node] = bb + sc[dl] - c;   // exclusive within bucket + bucket base
            dinv[node] = rsqrtf((float)(c + 1));
        }
    }
    for (int i = t; i < bc; i += 256) {
        unsigned v = ebuf[bb + i];
        int dl = v >> 17;
        int src = (int)(v & 0x1FFFFu);
        int rank = atomicAdd(&lcur[dl], 1);
        es[bb + sc[dl] - nh[dl] + rank] = src;
    }
}

// ---------- W (fp32, [256,128]) -> MFMA-fragment-packed bf16 hi/lo ----------
__global__ void k_prep_w(const float* __restrict__ W,
                         unsigned short* __restrict__ wb_hi,
                         unsigned short* __restrict__ wb_lo) {
    int t = blockIdx.x * 256 + threadIdx.x;   // 0..32767
    if (t >= IN_CH * OUT_CH) return;
    int j = t & 7;
    int lane = (t >> 3) & 63;
    int s = (t >> 9) & 7;
    int nt = t >> 12;
    int k = s * 32 + (lane >> 4) * 8 + j;
    int n = nt * 16 + (lane & 15);
    float w = W[k * OUT_CH + n];
    unsigned short hi = f2bf(w);
    wb_hi[t] = hi;
    wb_lo[t] = f2bf(w - bf2f(hi));
}

// ---------- h = x @ W  (fp32 in via split-bf16 MFMA) ----------
// Outputs: h (fp32, unscaled, self-loop) and hbs (bf16, pre-scaled by dinv[row]).
__global__ __launch_bounds__(512) void k_gemm(const float* __restrict__ x,
                                              const unsigned short* __restrict__ wb_hi,
                                              const unsigned short* __restrict__ wb_lo,
                                              const float* __restrict__ dinv,
                                              float* __restrict__ h,
                                              unsigned short* __restrict__ hbs) {
    __shared__ float xs[GEMM_ROWS * LDS_STRIDE];   // 33280 B
    int wv = threadIdx.x >> 6;        // 0..7 = n-tile
    int lane = threadIdx.x & 63;
    int row0 = blockIdx.x * GEMM_ROWS;

#pragma unroll
    for (int r = 0; r < 4; ++r) {
        int lr = wv * 4 + r;
        const float* src = x + (size_t)(row0 + lr) * IN_CH + lane * 4;
        __builtin_amdgcn_global_load_lds(
            (const __attribute__((address_space(1))) void*)src,
            (__attribute__((address_space(3))) void*)&xs[lr * LDS_STRIDE],
            16, 0, 0);
    }

    short8 Bh[8], Bl[8];
    const short8* bhp = (const short8*)wb_hi + (size_t)wv * 8 * 64 + lane;
    const short8* blp = (const short8*)wb_lo + (size_t)wv * 8 * 64 + lane;
#pragma unroll
    for (int s = 0; s < 8; ++s) {
        Bh[s] = bhp[s * 64];
        Bl[s] = blp[s * 64];
    }

    asm volatile("s_waitcnt vmcnt(0)" ::: "memory");
    __syncthreads();

    int r15 = lane & 15;
    int quad = lane >> 4;

    floatx4 acc[2];
#pragma unroll
    for (int ms = 0; ms < 2; ++ms) {
        acc[ms] = (floatx4){0.f, 0.f, 0.f, 0.f};
        const float* ap = xs + (ms * 16 + r15) * LDS_STRIDE + quad * 8;
#pragma unroll
        for (int s = 0; s < 8; ++s) {
            float4 v0 = *(const float4*)(ap + s * 32);
            float4 v1 = *(const float4*)(ap + s * 32 + 4);
            float xv[8] = {v0.x, v0.y, v0.z, v0.w, v1.x, v1.y, v1.z, v1.w};
            short8 ah, al;
#pragma unroll
            for (int j = 0; j < 8; ++j) {
                unsigned short hi = f2bf(xv[j]);
                ah[j] = (short)hi;
                al[j] = (short)f2bf(xv[j] - bf2f(hi));
            }
            acc[ms] = __builtin_amdgcn_mfma_f32_16x16x32_bf16(ah, Bh[s], acc[ms], 0, 0, 0);
            acc[ms] = __builtin_amdgcn_mfma_f32_16x16x32_bf16(ah, Bl[s], acc[ms], 0, 0, 0);
            acc[ms] = __builtin_amdgcn_mfma_f32_16x16x32_bf16(al, Bh[s], acc[ms], 0, 0, 0);
        }
    }

#pragma unroll
    for (int ms = 0; ms < 2; ++ms)
#pragma unroll
        for (int r = 0; r < 4; ++r) {
            int row = row0 + ms * 16 + quad * 4 + r;
            size_t idx = (size_t)row * OUT_CH + wv * 16 + r15;
            float v = acc[ms][r];
            h[idx] = v;
            hbs[idx] = f2bf(v * dinv[row]);
        }
}

// ---------- fused gather-aggregate + minmax scale + L2 normalize ----------
__global__ __launch_bounds__(256) void k_agg_fin(const float* __restrict__ h,
                                                 const unsigned short* __restrict__ hbs,
                                                 const float* __restrict__ dinv,
                                                 const int* __restrict__ es,
                                                 const int* __restrict__ base,
                                                 const int* __restrict__ cnt,
                                                 const float* __restrict__ b,
                                                 float* __restrict__ out) {
    int node = (blockIdx.x * 256 + threadIdx.x) >> 6;   // wave-uniform
    int lane = threadIdx.x & 63;
    if (node >= N_NODES) return;

    float dn = dinv[node];
    float2 hv = ((const float2*)(h + (size_t)node * OUT_CH))[lane];
    float2 bv = ((const float2*)b)[lane];

    int st = __builtin_amdgcn_readfirstlane(base[node]);
    int d  = __builtin_amdgcn_readfirstlane(cnt[node]);
    const int* ep = es + st;

    float ex = 0.f, ey = 0.f;   // edge sums of pre-scaled rows
    int j = 0;
    for (; j + 4 <= d; j += 4) {
        int s0 = __builtin_amdgcn_readfirstlane(ep[j + 0]);
        int s1 = __builtin_amdgcn_readfirstlane(ep[j + 1]);
        int s2 = __builtin_amdgcn_readfirstlane(ep[j + 2]);
        int s3 = __builtin_amdgcn_readfirstlane(ep[j + 3]);
        unsigned g0 = ((const unsigned*)(hbs + (size_t)s0 * OUT_CH))[lane];
        unsigned g1 = ((const unsigned*)(hbs + (size_t)s1 * OUT_CH))[lane];
        unsigned g2 = ((const unsigned*)(hbs + (size_t)s2 * OUT_CH))[lane];
        unsigned g3 = ((const unsigned*)(hbs + (size_t)s3 * OUT_CH))[lane];
        ex += __uint_as_float(g0 << 16);
        ey += __uint_as_float(g0 & 0xffff0000u);
        ex += __uint_as_float(g1 << 16);
        ey += __uint_as_float(g1 & 0xffff0000u);
        ex += __uint_as_float(g2 << 16);
        ey += __uint_as_float(g2 & 0xffff0000u);
        ex += __uint_as_float(g3 << 16);
        ey += __uint_as_float(g3 & 0xffff0000u);
    }
    for (; j < d; ++j) {
        int s0 = __builtin_amdgcn_readfirstlane(ep[j]);
        unsigned g0 = ((const unsigned*)(hbs + (size_t)s0 * OUT_CH))[lane];
        ex += __uint_as_float(g0 << 16);
        ey += __uint_as_float(g0 & 0xffff0000u);
    }

    float w0 = dn * dn;
    float2 acc;
    acc.x = hv.x * w0 + bv.x + dn * ex;
    acc.y = hv.y * w0 + bv.y + dn * ey;

    // min-max scale
    float lmin = fminf(acc.x, acc.y), lmax = fmaxf(acc.x, acc.y);
#pragma unroll
    for (int m = 32; m; m >>= 1) {
        lmin = fminf(lmin, __shfl_xor(lmin, m, 64));
        lmax = fmaxf(lmax, __shfl_xor(lmax, m, 64));
    }
    float scale = 1.0f / (lmax - lmin);
    float zx = (acc.x - lmin) * scale;
    float zy = (acc.y - lmin) * scale;
    // L2 normalize
    float ss = zx * zx + zy * zy;
#pragma unroll
    for (int m = 32; m; m >>= 1) ss += __shfl_xor(ss, m, 64);
    float inv = 1.0f / fmaxf(sqrtf(ss), 1e-12f);
    float2 o;
    o.x = zx * inv;
    o.y = zy * inv;
    ((float2*)(out + (size_t)node * OUT_CH))[lane] = o;
}

extern "C" void kernel_launch(void* const* d_in, const int* in_sizes, int n_in,
                              void* d_out, int out_size, void* d_ws, size_t ws_size,
                              hipStream_t stream) {
    const float* x = (const float*)d_in[0];        // fp32 [N, 256]
    const int* ei = (const int*)d_in[1];           // int32 [2, E]
    const float* W = (const float*)d_in[2];        // fp32 [256, 128]
    const float* b = (const float*)d_in[3];        // fp32 [128]
    float* out = (float*)d_out;                    // fp32 [N, 128]

    char* ws = (char*)d_ws;
    size_t o = 0;
    auto alloc = [&](size_t bytes) { void* p = ws + o; o = (o + bytes + 255) & ~(size_t)255; return p; };
    float* dinv    = (float*)alloc((size_t)N_NODES * 4);
    int*   cnt     = (int*)  alloc((size_t)N_NODES * 4);
    int*   base    = (int*)  alloc((size_t)N_NODES * 4);
    int*   bhist   = (int*)  alloc(NBUCK * 4);
    int*   bbase   = (int*)  alloc(NBUCK * 4);
    int*   bcursor = (int*)  alloc(NBUCK * 4);
    unsigned short* wb_hi = (unsigned short*)alloc((size_t)IN_CH * OUT_CH * 2);
    unsigned short* wb_lo = (unsigned short*)alloc((size_t)IN_CH * OUT_CH * 2);
    float* h       = (float*)alloc((size_t)N_NODES * OUT_CH * 4);
    unsigned short* hbs = (unsigned short*)alloc((size_t)N_NODES * OUT_CH * 2);
    unsigned* ebuf = (unsigned*)alloc((size_t)N_EDGES * 4);
    int*   es      = (int*)  alloc((size_t)N_EDGES * 4);

    const int* rows = ei;
    const int* cols = ei + N_EDGES;

    // CSR build (two-level bucketed counting sort)
    pa_zero<<<1, 256, 0, stream>>>(bhist);
    pa_hist<<<(N_EDGES + CHH - 1) / CHH, 256, 0, stream>>>(cols, bhist);
    pa_scan<<<1, 256, 0, stream>>>(bhist, bbase, bcursor);
    pa_scatter<<<(N_EDGES + CSC - 1) / CSC, 256, 0, stream>>>(rows, cols, bcursor, ebuf);
    pb_build<<<NBUCK, 256, 0, stream>>>(ebuf, bhist, bbase, cnt, base, dinv, es);

    // GEMM
    k_prep_w<<<(IN_CH * OUT_CH + 255) / 256, 256, 0, stream>>>(W, wb_hi, wb_lo);
    k_gemm<<<N_NODES / GEMM_ROWS, 512, 0, stream>>>(x, wb_hi, wb_lo, dinv, h, hbs);

    // fused aggregate + scale + normalize
    k_agg_fin<<<(N_NODES + 3) / 4, 256, 0, stream>>>(h, hbs, dinv, es, base, cnt, b, out);
}